// Round 5
// baseline (185.306 us; speedup 1.0000x reference)
//
#include <hip/hip_runtime.h>
#include <math.h>

#define B_   8
#define M_   4096
#define N_   4096
#define DM   1024
#define DC   768
#define DH   16
#define CHUNKS 64
#define LDSTRIDE 132      // 128 + 4 pad (bank skew)
#define QROWS 16
#define PROWS 32

__device__ __forceinline__ float elu1(float t) {
    return t > 0.0f ? t + 1.0f : expf(t);
}
__device__ __forceinline__ float4 ld4(const float* p) { return *reinterpret_cast<const float4*>(p); }
__device__ __forceinline__ void  st4(float* p, float4 v) { *reinterpret_cast<float4*>(p) = v; }
__device__ __forceinline__ float4 sx4(float4 v, int m) {
    float4 r;
    r.x = __shfl_xor(v.x, m); r.y = __shfl_xor(v.y, m);
    r.z = __shfl_xor(v.z, m); r.w = __shfl_xor(v.w, m);
    return r;
}
__device__ __forceinline__ float4 add4(float4 a, float4 b) {
    float4 r; r.x=a.x+b.x; r.y=a.y+b.y; r.z=a.z+b.z; r.w=a.w+b.w; return r;
}
__device__ __forceinline__ void fma4(float4& a, float s, float4 w) {
    a.x = fmaf(s, w.x, a.x); a.y = fmaf(s, w.y, a.y);
    a.z = fmaf(s, w.z, a.z); a.w = fmaf(s, w.w, a.w);
}

// ---------------------------------------------------------------------------
// kvr_kernel: K = elu1(ctx@Wk+bk), V = ctx@Wv+bv  (kept in LDS), then the
// per-64-row partial KtV (16x16) + Ksum (16) reduction fused in-block.
// grid = B*N/64 = 512
// ---------------------------------------------------------------------------
__global__ __launch_bounds__(256, 2) void kvr_kernel(
    const float* __restrict__ ctx,
    const float* __restrict__ Wk, const float* __restrict__ bk,
    const float* __restrict__ Wv, const float* __restrict__ bv,
    float* __restrict__ part)
{
    __shared__ float xt[64 * LDSTRIDE];
    __shared__ float sk[64][DH];
    __shared__ float sv[64][DH];
    const int t = threadIdx.x;
    const int q = t & 3;
    const int s = (t >> 2) & 3;
    const int g = t >> 4;
    const size_t row0 = (size_t)blockIdx.x * 64;

    float4 ka[4], va[4];
    #pragma unroll
    for (int r = 0; r < 4; ++r) { ka[r] = make_float4(0,0,0,0); va[r] = make_float4(0,0,0,0); }

    for (int ch = 0; ch < DC/128; ++ch) {
        #pragma unroll
        for (int i = 0; i < 8; ++i) {
            const int id = t + i*256;
            const int r  = id >> 5;
            const int c  = id & 31;
            st4(&xt[r*LDSTRIDE + c*4], ld4(ctx + (row0 + r)*DC + ch*128 + c*4));
        }
        __syncthreads();

        #pragma unroll
        for (int kk = 0; kk < 8; ++kk) {
            const int kl = kk*16 + s*4;
            const int kg = ch*128 + kl;
            const float4 wk0 = ld4(Wk + (size_t)(kg+0)*DH + q*4);
            const float4 wk1 = ld4(Wk + (size_t)(kg+1)*DH + q*4);
            const float4 wk2 = ld4(Wk + (size_t)(kg+2)*DH + q*4);
            const float4 wk3 = ld4(Wk + (size_t)(kg+3)*DH + q*4);
            const float4 wv0 = ld4(Wv + (size_t)(kg+0)*DH + q*4);
            const float4 wv1 = ld4(Wv + (size_t)(kg+1)*DH + q*4);
            const float4 wv2 = ld4(Wv + (size_t)(kg+2)*DH + q*4);
            const float4 wv3 = ld4(Wv + (size_t)(kg+3)*DH + q*4);
            #pragma unroll
            for (int r = 0; r < 4; ++r) {
                const float4 xv = ld4(&xt[(g*4 + r)*LDSTRIDE + kl]);
                fma4(ka[r], xv.x, wk0); fma4(ka[r], xv.y, wk1);
                fma4(ka[r], xv.z, wk2); fma4(ka[r], xv.w, wk3);
                fma4(va[r], xv.x, wv0); fma4(va[r], xv.y, wv1);
                fma4(va[r], xv.z, wv2); fma4(va[r], xv.w, wv3);
            }
        }
        __syncthreads();
    }

    #pragma unroll
    for (int r = 0; r < 4; ++r) {
        ka[r] = add4(ka[r], sx4(ka[r], 4)); ka[r] = add4(ka[r], sx4(ka[r], 8));
        va[r] = add4(va[r], sx4(va[r], 4)); va[r] = add4(va[r], sx4(va[r], 8));
    }

    if (s == 0) {
        const float4 b4 = ld4(bk + q*4);
        #pragma unroll
        for (int r = 0; r < 4; ++r) {
            float4 o;
            o.x = elu1(ka[r].x + b4.x); o.y = elu1(ka[r].y + b4.y);
            o.z = elu1(ka[r].z + b4.z); o.w = elu1(ka[r].w + b4.w);
            st4(&sk[g*4 + r][q*4], o);
        }
    } else if (s == 1) {
        const float4 b4 = ld4(bv + q*4);
        #pragma unroll
        for (int r = 0; r < 4; ++r) {
            float4 o;
            o.x = va[r].x + b4.x; o.y = va[r].y + b4.y;
            o.z = va[r].z + b4.z; o.w = va[r].w + b4.w;
            st4(&sv[g*4 + r][q*4], o);
        }
    }
    __syncthreads();

    // fused reduce: thread (d,e) accumulates sum_n K[n][d]*V[n][e]
    const int d = t >> 4, e = t & 15;
    float acc = 0.f;
    #pragma unroll 16
    for (int n = 0; n < 64; ++n) acc += sk[n][d] * sv[n][e];
    float* p = part + (size_t)blockIdx.x * 272;
    p[t] = acc;
    if (t < DH) {
        float ss = 0.f;
        #pragma unroll 16
        for (int n = 0; n < 64; ++n) ss += sk[n][t];
        p[256 + t] = ss;
    }
}

// ---------------------------------------------------------------------------
// reduce2: combine partials -> comb[b][272] (256 KtV d-major + 16 Ksum)
// ---------------------------------------------------------------------------
__global__ __launch_bounds__(320) void reduce2(
    const float* __restrict__ part, float* __restrict__ comb)
{
    const int b = blockIdx.x;
    const int t = threadIdx.x;
    if (t < 272) {
        float s = 0.f;
        #pragma unroll
        for (int ch = 0; ch < CHUNKS; ++ch)
            s += part[((size_t)b*CHUNKS + ch) * 272 + t];
        comb[(size_t)b*272 + t] = s;
    }
}

// ---------------------------------------------------------------------------
// q_kernel: Q = elu1(x@Wq+bq); o = (Q@KtV)/(Q.Ksum+1e-6) -> o_ws
// 16 rows/block, grid = B*M/16 = 2048, LDS ~19KB, VGPR forced <=64
// Double-buffered LDS with early global-load issue; 1 sync per chunk.
// ---------------------------------------------------------------------------
__global__ __launch_bounds__(256, 8) void q_kernel(
    const float* __restrict__ x,
    const float* __restrict__ Wq, const float* __restrict__ bq,
    const float* __restrict__ comb,
    float* __restrict__ o_ws)
{
    __shared__ float xt[2][QROWS * LDSTRIDE];
    __shared__ float qt[QROWS * DH];
    __shared__ float kts[272];

    const int t = threadIdx.x;
    const int q = t & 3;
    const int s = (t >> 2) & 3;
    const int g = t >> 4;                    // 0..15, owns row g
    const size_t row0 = (size_t)blockIdx.x * QROWS;
    const int b = blockIdx.x >> 8;           // 256 blocks per batch
    const float* xbase = x + row0 * DM;

    const int rb = t >> 5;                   // staging rows rb, rb+8
    const int c4 = (t & 31) * 4;

    float4 accA = make_float4(0,0,0,0), accB = make_float4(0,0,0,0);
    float4 A0, A1, B0, B1;

#define SLOAD(ch, R0, R1) { \
    R0 = ld4(xbase + (size_t)rb*DM + (ch)*128 + c4); \
    R1 = ld4(xbase + (size_t)(rb+8)*DM + (ch)*128 + c4); }
#define SWRITE(pb, R0, R1) { \
    st4(&xt[pb][rb*LDSTRIDE + c4], R0); \
    st4(&xt[pb][(rb+8)*LDSTRIDE + c4], R1); }
#define COMPUTE(ch, pb) { \
    _Pragma("unroll") for (int kk = 0; kk < 8; ++kk) { \
        const int kl = kk*16 + s*4; \
        const int kg = (ch)*128 + kl; \
        const float4 w0 = ld4(Wq + (size_t)(kg+0)*DH + q*4); \
        const float4 w1 = ld4(Wq + (size_t)(kg+1)*DH + q*4); \
        const float4 w2 = ld4(Wq + (size_t)(kg+2)*DH + q*4); \
        const float4 w3 = ld4(Wq + (size_t)(kg+3)*DH + q*4); \
        const float4 xv = ld4(&xt[pb][g*LDSTRIDE + kl]); \
        float4& ac = (kk & 1) ? accB : accA; \
        fma4(ac, xv.x, w0); fma4(ac, xv.y, w1); \
        fma4(ac, xv.z, w2); fma4(ac, xv.w, w3); } }

    SLOAD(0, A0, A1);
    SWRITE(0, A0, A1);
    #pragma unroll
    for (int cc = 0; cc < 4; ++cc) {
        const int ch = cc*2;
        __syncthreads();
        if (ch < 7) SLOAD(ch+1, B0, B1);
        COMPUTE(ch, 0);
        if (ch < 7) SWRITE(1, B0, B1);
        __syncthreads();
        if (ch < 6) SLOAD(ch+2, A0, A1);
        COMPUTE(ch+1, 1);
        if (ch < 6) SWRITE(0, A0, A1);
    }
#undef SLOAD
#undef SWRITE
#undef COMPUTE

    float4 acc = add4(accA, accB);
    acc = add4(acc, sx4(acc, 4));
    acc = add4(acc, sx4(acc, 8));

    if (s == 0) {
        const float4 b4 = ld4(bq + q*4);
        float4 o;
        o.x = elu1(acc.x + b4.x); o.y = elu1(acc.y + b4.y);
        o.z = elu1(acc.z + b4.z); o.w = elu1(acc.w + b4.w);
        st4(&qt[g*DH + q*4], o);
    }
    if (t < 68) st4(&kts[t*4], ld4(comb + (size_t)b*272 + t*4));
    __syncthreads();

    // o per row: threads 0..63 -> row t>>2, out-dims (t&3)*4..+4
    if (t < 64) {
        const float* qrow = &qt[(t >> 2) * DH];
        const int jj = (t & 3) * 4;
        float den = 1e-6f;
        float4 num = make_float4(0,0,0,0);
        #pragma unroll
        for (int d4 = 0; d4 < 4; ++d4) {
            const float4 q4  = ld4(&qrow[d4*4]);
            const float4 ks4 = ld4(&kts[256 + d4*4]);
            den += q4.x*ks4.x + q4.y*ks4.y + q4.z*ks4.z + q4.w*ks4.w;
            fma4(num, q4.x, ld4(&kts[(d4*4+0)*DH + jj]));
            fma4(num, q4.y, ld4(&kts[(d4*4+1)*DH + jj]));
            fma4(num, q4.z, ld4(&kts[(d4*4+2)*DH + jj]));
            fma4(num, q4.w, ld4(&kts[(d4*4+3)*DH + jj]));
        }
        const float inv = 1.0f / den;
        float4 o4; o4.x = num.x*inv; o4.y = num.y*inv; o4.z = num.z*inv; o4.w = num.w*inv;
        st4(o_ws + (row0 + (t >> 2))*DH + jj, o4);
    }
}

// ---------------------------------------------------------------------------
// proj_kernel: out = o @ Wo + bo.  Pure streaming store kernel.
// block 256, thread owns cols 4t..4t+3 for PROWS rows; Wo in registers.
// grid = B*M/PROWS = 1024. No LDS, no syncs.
// ---------------------------------------------------------------------------
__global__ __launch_bounds__(256) void proj_kernel(
    const float* __restrict__ o_ws,
    const float* __restrict__ Wo, const float* __restrict__ bo,
    float* __restrict__ out)
{
    const int t = threadIdx.x;
    const size_t row0 = (size_t)blockIdx.x * PROWS;
    float4 wreg[16];
    #pragma unroll
    for (int e = 0; e < 16; ++e) wreg[e] = ld4(Wo + (size_t)e*DM + t*4);
    const float4 bov = ld4(bo + t*4);

    #pragma unroll 4
    for (int r = 0; r < PROWS; ++r) {
        const float* orow = o_ws + (row0 + r)*DH;
        float4 a = bov;
        #pragma unroll
        for (int eo = 0; eo < 4; ++eo) {
            const float4 o4 = ld4(orow + eo*4);
            fma4(a, o4.x, wreg[eo*4+0]); fma4(a, o4.y, wreg[eo*4+1]);
            fma4(a, o4.z, wreg[eo*4+2]); fma4(a, o4.w, wreg[eo*4+3]);
        }
        st4(out + (row0 + r)*DM + t*4, a);
    }
}

// ---------------------------------------------------------------------------
extern "C" void kernel_launch(void* const* d_in, const int* in_sizes, int n_in,
                              void* d_out, int out_size, void* d_ws, size_t ws_size,
                              hipStream_t stream) {
    const float* x    = (const float*)d_in[0];
    const float* ctx  = (const float*)d_in[1];
    const float* Wq   = (const float*)d_in[2];
    const float* bq   = (const float*)d_in[3];
    const float* Wk   = (const float*)d_in[4];
    const float* bk   = (const float*)d_in[5];
    const float* Wv   = (const float*)d_in[6];
    const float* bv   = (const float*)d_in[7];
    const float* Wo   = (const float*)d_in[8];
    const float* bo   = (const float*)d_in[9];
    float* out = (float*)d_out;

    float* ws = (float*)d_ws;
    float* part = ws;                               // 512*272 = 139264
    float* comb = part + (size_t)512*272;           // 8*272   = 2176
    float* o_ws = comb + (size_t)B_*272;            // 32768*16 = 524288

    kvr_kernel<<<dim3(B_*N_/64), dim3(256), 0, stream>>>(ctx, Wk, bk, Wv, bv, part);
    reduce2<<<dim3(B_), dim3(320), 0, stream>>>(part, comb);
    q_kernel<<<dim3(B_*M_/QROWS), dim3(256), 0, stream>>>(x, Wq, bq, comb, o_ws);
    proj_kernel<<<dim3(B_*M_/PROWS), dim3(256), 0, stream>>>(o_ws, Wo, bo, out);
}

// Round 6
// 151.456 us; speedup vs baseline: 1.2235x; 1.2235x over previous
//
#include <hip/hip_runtime.h>
#include <math.h>

#define B_   8
#define M_   4096
#define N_   4096
#define DM   1024
#define DC   768
#define DH   16
#define CHUNKS 64
#define LDSTRIDE 132      // kvr: 128 + 4 pad
#define QSTRIDE 66        // q_kernel: 64 + 2 pad (2-way max aliasing)

__device__ __forceinline__ float elu1(float t) {
    return t > 0.0f ? t + 1.0f : expf(t);
}
__device__ __forceinline__ float4 ld4(const float* p) { return *reinterpret_cast<const float4*>(p); }
__device__ __forceinline__ void  st4(float* p, float4 v) { *reinterpret_cast<float4*>(p) = v; }
__device__ __forceinline__ float4 sx4(float4 v, int m) {
    float4 r;
    r.x = __shfl_xor(v.x, m); r.y = __shfl_xor(v.y, m);
    r.z = __shfl_xor(v.z, m); r.w = __shfl_xor(v.w, m);
    return r;
}
__device__ __forceinline__ float4 add4(float4 a, float4 b) {
    float4 r; r.x=a.x+b.x; r.y=a.y+b.y; r.z=a.z+b.z; r.w=a.w+b.w; return r;
}
__device__ __forceinline__ void fma4(float4& a, float s, float4 w) {
    a.x = fmaf(s, w.x, a.x); a.y = fmaf(s, w.y, a.y);
    a.z = fmaf(s, w.z, a.z); a.w = fmaf(s, w.w, a.w);
}

// ---------------------------------------------------------------------------
// kvr_kernel: K = elu1(ctx@Wk+bk), V = ctx@Wv+bv (LDS only), fused partial
// KtV (16x16) + Ksum per 64-row block. grid = B*N/64 = 512.
// ---------------------------------------------------------------------------
__global__ __launch_bounds__(256, 2) void kvr_kernel(
    const float* __restrict__ ctx,
    const float* __restrict__ Wk, const float* __restrict__ bk,
    const float* __restrict__ Wv, const float* __restrict__ bv,
    float* __restrict__ part)
{
    __shared__ float xt[64 * LDSTRIDE];
    __shared__ float sk[64][DH];
    __shared__ float sv[64][DH];
    const int t = threadIdx.x;
    const int q = t & 3;
    const int s = (t >> 2) & 3;
    const int g = t >> 4;
    const size_t row0 = (size_t)blockIdx.x * 64;

    float4 ka[4], va[4];
    #pragma unroll
    for (int r = 0; r < 4; ++r) { ka[r] = make_float4(0,0,0,0); va[r] = make_float4(0,0,0,0); }

    for (int ch = 0; ch < DC/128; ++ch) {
        #pragma unroll
        for (int i = 0; i < 8; ++i) {
            const int id = t + i*256;
            const int r  = id >> 5;
            const int c  = id & 31;
            st4(&xt[r*LDSTRIDE + c*4], ld4(ctx + (row0 + r)*DC + ch*128 + c*4));
        }
        __syncthreads();

        #pragma unroll
        for (int kk = 0; kk < 8; ++kk) {
            const int kl = kk*16 + s*4;
            const int kg = ch*128 + kl;
            const float4 wk0 = ld4(Wk + (size_t)(kg+0)*DH + q*4);
            const float4 wk1 = ld4(Wk + (size_t)(kg+1)*DH + q*4);
            const float4 wk2 = ld4(Wk + (size_t)(kg+2)*DH + q*4);
            const float4 wk3 = ld4(Wk + (size_t)(kg+3)*DH + q*4);
            const float4 wv0 = ld4(Wv + (size_t)(kg+0)*DH + q*4);
            const float4 wv1 = ld4(Wv + (size_t)(kg+1)*DH + q*4);
            const float4 wv2 = ld4(Wv + (size_t)(kg+2)*DH + q*4);
            const float4 wv3 = ld4(Wv + (size_t)(kg+3)*DH + q*4);
            #pragma unroll
            for (int r = 0; r < 4; ++r) {
                const float4 xv = ld4(&xt[(g*4 + r)*LDSTRIDE + kl]);
                fma4(ka[r], xv.x, wk0); fma4(ka[r], xv.y, wk1);
                fma4(ka[r], xv.z, wk2); fma4(ka[r], xv.w, wk3);
                fma4(va[r], xv.x, wv0); fma4(va[r], xv.y, wv1);
                fma4(va[r], xv.z, wv2); fma4(va[r], xv.w, wv3);
            }
        }
        __syncthreads();
    }

    #pragma unroll
    for (int r = 0; r < 4; ++r) {
        ka[r] = add4(ka[r], sx4(ka[r], 4)); ka[r] = add4(ka[r], sx4(ka[r], 8));
        va[r] = add4(va[r], sx4(va[r], 4)); va[r] = add4(va[r], sx4(va[r], 8));
    }

    if (s == 0) {
        const float4 b4 = ld4(bk + q*4);
        #pragma unroll
        for (int r = 0; r < 4; ++r) {
            float4 o;
            o.x = elu1(ka[r].x + b4.x); o.y = elu1(ka[r].y + b4.y);
            o.z = elu1(ka[r].z + b4.z); o.w = elu1(ka[r].w + b4.w);
            st4(&sk[g*4 + r][q*4], o);
        }
    } else if (s == 1) {
        const float4 b4 = ld4(bv + q*4);
        #pragma unroll
        for (int r = 0; r < 4; ++r) {
            float4 o;
            o.x = va[r].x + b4.x; o.y = va[r].y + b4.y;
            o.z = va[r].z + b4.z; o.w = va[r].w + b4.w;
            st4(&sv[g*4 + r][q*4], o);
        }
    }
    __syncthreads();

    const int d = t >> 4, e = t & 15;
    float acc = 0.f;
    #pragma unroll 16
    for (int n = 0; n < 64; ++n) acc += sk[n][d] * sv[n][e];
    float* p = part + (size_t)blockIdx.x * 272;
    p[t] = acc;
    if (t < DH) {
        float ss = 0.f;
        #pragma unroll 16
        for (int n = 0; n < 64; ++n) ss += sk[n][t];
        p[256 + t] = ss;
    }
}

// ---------------------------------------------------------------------------
// reduce2: combine partials -> comb[b][272]
// ---------------------------------------------------------------------------
__global__ __launch_bounds__(320) void reduce2(
    const float* __restrict__ part, float* __restrict__ comb)
{
    const int b = blockIdx.x;
    const int t = threadIdx.x;
    if (t < 272) {
        float s = 0.f;
        #pragma unroll
        for (int ch = 0; ch < CHUNKS; ++ch)
            s += part[((size_t)b*CHUNKS + ch) * 272 + t];
        comb[(size_t)b*272 + t] = s;
    }
}

// ---------------------------------------------------------------------------
// q_kernel v4: 128 threads, 64 rows/block, 8 rows/thread (weight ratio 32:1).
// 16 chunks of 64 cols; double-buffered async staging; Wq slice/chunk = 4KB
// (L1-hot). grid = B*M/64 = 512.
// thread: q=t&3 (4 dims), s=(t>>2)&3 (k-slot), g=t>>4 (rows g*8..g*8+7)
// ---------------------------------------------------------------------------
__global__ __launch_bounds__(128) void q_kernel(
    const float* __restrict__ x,
    const float* __restrict__ Wq, const float* __restrict__ bq,
    const float* __restrict__ comb,
    float* __restrict__ o_ws)
{
    __shared__ float xt[2][64 * QSTRIDE];
    __shared__ float qt[64 * DH];
    __shared__ float kts[272];

    const int t = threadIdx.x;
    const int q = t & 3;
    const int s = (t >> 2) & 3;
    const int g = t >> 4;                    // 0..7, owns rows g*8..g*8+7
    const size_t row0 = (size_t)blockIdx.x * 64;
    const int b = blockIdx.x >> 6;           // 64 blocks per batch
    const float* xbase = x + row0 * DM;

    float4 acc[8];
    #pragma unroll
    for (int r = 0; r < 8; ++r) acc[r] = make_float4(0,0,0,0);
    float4 A[8], Bf[8];

    // staging map: id = t + i*128; row = id>>4 (16 f4 per 64-col row)
#define SLOAD(ch, buf) { \
    _Pragma("unroll") for (int i = 0; i < 8; ++i) { \
        const int id = t + i*128; \
        buf[i] = ld4(xbase + (size_t)(id >> 4)*DM + (ch)*64 + (id & 15)*4); } }
#define SWRITE(pb, buf) { \
    _Pragma("unroll") for (int i = 0; i < 8; ++i) { \
        const int id = t + i*128; \
        st4(&xt[pb][(id >> 4)*QSTRIDE + (id & 15)*4], buf[i]); } }
#define COMPUTE(ch, pb) { \
    _Pragma("unroll") for (int kk = 0; kk < 4; ++kk) { \
        const int kl = kk*16 + s*4; \
        const int kg = (ch)*64 + kl; \
        const float4 w0 = ld4(Wq + (size_t)(kg+0)*DH + q*4); \
        const float4 w1 = ld4(Wq + (size_t)(kg+1)*DH + q*4); \
        const float4 w2 = ld4(Wq + (size_t)(kg+2)*DH + q*4); \
        const float4 w3 = ld4(Wq + (size_t)(kg+3)*DH + q*4); \
        _Pragma("unroll") for (int r = 0; r < 8; ++r) { \
            const float4 xv = ld4(&xt[pb][(g*8 + r)*QSTRIDE + kl]); \
            fma4(acc[r], xv.x, w0); fma4(acc[r], xv.y, w1); \
            fma4(acc[r], xv.z, w2); fma4(acc[r], xv.w, w3); } } }

    SLOAD(0, A);
    SWRITE(0, A);
    #pragma unroll
    for (int cc = 0; cc < 8; ++cc) {
        const int ch = cc*2;
        __syncthreads();
        SLOAD(ch+1, Bf);                 // ch+1 <= 15 always
        COMPUTE(ch, 0);
        SWRITE(1, Bf);
        __syncthreads();
        if (ch < 14) SLOAD(ch+2, A);
        COMPUTE(ch+1, 1);
        if (ch < 14) SWRITE(0, A);
    }
#undef SLOAD
#undef SWRITE
#undef COMPUTE

    // combine the 4 k-slots (lanes differing in bits 2,3)
    #pragma unroll
    for (int r = 0; r < 8; ++r) {
        acc[r] = add4(acc[r], sx4(acc[r], 4));
        acc[r] = add4(acc[r], sx4(acc[r], 8));
    }

    if (s == 0) {
        const float4 b4 = ld4(bq + q*4);
        #pragma unroll
        for (int r = 0; r < 8; ++r) {
            float4 o;
            o.x = elu1(acc[r].x + b4.x); o.y = elu1(acc[r].y + b4.y);
            o.z = elu1(acc[r].z + b4.z); o.w = elu1(acc[r].w + b4.w);
            st4(&qt[(g*8 + r)*DH + q*4], o);
        }
    }
    if (t < 68) st4(&kts[t*4], ld4(comb + (size_t)b*272 + t*4));
    __syncthreads();

    // o per row: thread -> row t>>1, out-dim half (t&1)*8..+8
    {
        const int row = t >> 1;
        const int jj = (t & 1) * 8;
        const float* qrow = &qt[row * DH];
        float den = 1e-6f;
        float4 n0 = make_float4(0,0,0,0), n1 = make_float4(0,0,0,0);
        #pragma unroll
        for (int d4 = 0; d4 < 4; ++d4) {
            const float4 q4  = ld4(&qrow[d4*4]);
            const float4 ks4 = ld4(&kts[256 + d4*4]);
            den += q4.x*ks4.x + q4.y*ks4.y + q4.z*ks4.z + q4.w*ks4.w;
            const float qv[4] = {q4.x, q4.y, q4.z, q4.w};
            #pragma unroll
            for (int u = 0; u < 4; ++u) {
                const int d = d4*4 + u;
                fma4(n0, qv[u], ld4(&kts[d*DH + jj]));
                fma4(n1, qv[u], ld4(&kts[d*DH + jj + 4]));
            }
        }
        const float inv = 1.0f / den;
        float4 o0, o1;
        o0.x=n0.x*inv; o0.y=n0.y*inv; o0.z=n0.z*inv; o0.w=n0.w*inv;
        o1.x=n1.x*inv; o1.y=n1.y*inv; o1.z=n1.z*inv; o1.w=n1.w*inv;
        st4(o_ws + (row0 + row)*DH + jj,     o0);
        st4(o_ws + (row0 + row)*DH + jj + 4, o1);
    }
}

// ---------------------------------------------------------------------------
// proj_kernel: out = o @ Wo + bo. o staged once in LDS (broadcast reads),
// Wo in registers, 1KB/wave coalesced stores. 64 rows/block, grid = 512.
// ---------------------------------------------------------------------------
__global__ __launch_bounds__(256) void proj_kernel(
    const float* __restrict__ o_ws,
    const float* __restrict__ Wo, const float* __restrict__ bo,
    float* __restrict__ out)
{
    __shared__ float ol[64 * DH];
    const int t = threadIdx.x;
    const size_t row0 = (size_t)blockIdx.x * 64;

    st4(&ol[t*4], ld4(o_ws + row0*DH + t*4));   // 256 thr * f4 = 1024 floats
    float4 wreg[16];
    #pragma unroll
    for (int e = 0; e < 16; ++e) wreg[e] = ld4(Wo + (size_t)e*DM + t*4);
    const float4 bov = ld4(bo + t*4);
    __syncthreads();

    #pragma unroll 4
    for (int r = 0; r < 64; ++r) {
        float4 a = bov;
        #pragma unroll
        for (int eo = 0; eo < 4; ++eo) {
            const float4 o4 = ld4(&ol[r*DH + eo*4]);
            fma4(a, o4.x, wreg[eo*4+0]); fma4(a, o4.y, wreg[eo*4+1]);
            fma4(a, o4.z, wreg[eo*4+2]); fma4(a, o4.w, wreg[eo*4+3]);
        }
        st4(out + (row0 + r)*DM + t*4, a);
    }
}

// ---------------------------------------------------------------------------
extern "C" void kernel_launch(void* const* d_in, const int* in_sizes, int n_in,
                              void* d_out, int out_size, void* d_ws, size_t ws_size,
                              hipStream_t stream) {
    const float* x    = (const float*)d_in[0];
    const float* ctx  = (const float*)d_in[1];
    const float* Wq   = (const float*)d_in[2];
    const float* bq   = (const float*)d_in[3];
    const float* Wk   = (const float*)d_in[4];
    const float* bk   = (const float*)d_in[5];
    const float* Wv   = (const float*)d_in[6];
    const float* bv   = (const float*)d_in[7];
    const float* Wo   = (const float*)d_in[8];
    const float* bo   = (const float*)d_in[9];
    float* out = (float*)d_out;

    float* ws = (float*)d_ws;
    float* part = ws;                               // 512*272
    float* comb = part + (size_t)512*272;           // 8*272
    float* o_ws = comb + (size_t)B_*272;            // 32768*16

    kvr_kernel<<<dim3(B_*N_/64), dim3(256), 0, stream>>>(ctx, Wk, bk, Wv, bv, part);
    reduce2<<<dim3(B_), dim3(320), 0, stream>>>(part, comb);
    q_kernel<<<dim3(B_*M_/64), dim3(128), 0, stream>>>(x, Wq, bq, comb, o_ws);
    proj_kernel<<<dim3(B_*M_/64), dim3(256), 0, stream>>>(o_ws, Wo, bo, out);
}

// Round 7
// 118.515 us; speedup vs baseline: 1.5636x; 1.2779x over previous
//
#include <hip/hip_runtime.h>
#include <math.h>

#define B_   8
#define M_   4096
#define N_   4096
#define DM   1024
#define DC   768
#define DH   16
#define CHUNKS 64
#define LDSTRIDE 132      // 128 + 4 pad

typedef float v4f __attribute__((ext_vector_type(4)));

__device__ __forceinline__ float elu1(float t) {
    return t > 0.0f ? t + 1.0f : expf(t);
}
__device__ __forceinline__ float4 ld4(const float* p) { return *reinterpret_cast<const float4*>(p); }
__device__ __forceinline__ void  st4(float* p, float4 v) { *reinterpret_cast<float4*>(p) = v; }
__device__ __forceinline__ void  st4nt(float* p, float4 v) {
    v4f w; w.x = v.x; w.y = v.y; w.z = v.z; w.w = v.w;
    __builtin_nontemporal_store(w, reinterpret_cast<v4f*>(p));
}
__device__ __forceinline__ float4 sx4(float4 v, int m) {
    float4 r;
    r.x = __shfl_xor(v.x, m); r.y = __shfl_xor(v.y, m);
    r.z = __shfl_xor(v.z, m); r.w = __shfl_xor(v.w, m);
    return r;
}
__device__ __forceinline__ float4 add4(float4 a, float4 b) {
    float4 r; r.x=a.x+b.x; r.y=a.y+b.y; r.z=a.z+b.z; r.w=a.w+b.w; return r;
}
__device__ __forceinline__ void fma4(float4& a, float s, float4 w) {
    a.x = fmaf(s, w.x, a.x); a.y = fmaf(s, w.y, a.y);
    a.z = fmaf(s, w.z, a.z); a.w = fmaf(s, w.w, a.w);
}

// ---------------------------------------------------------------------------
// kvr_kernel: K = elu1(ctx@Wk+bk), V = ctx@Wv+bv (LDS only), fused partial
// KtV (16x16) + Ksum per 64-row block. grid = B*N/64 = 512. (proven ~5 TB/s)
// ---------------------------------------------------------------------------
__global__ __launch_bounds__(256, 2) void kvr_kernel(
    const float* __restrict__ ctx,
    const float* __restrict__ Wk, const float* __restrict__ bk,
    const float* __restrict__ Wv, const float* __restrict__ bv,
    float* __restrict__ part)
{
    __shared__ float xt[64 * LDSTRIDE];
    __shared__ float sk[64][DH];
    __shared__ float sv[64][DH];
    const int t = threadIdx.x;
    const int q = t & 3;
    const int s = (t >> 2) & 3;
    const int g = t >> 4;
    const size_t row0 = (size_t)blockIdx.x * 64;

    float4 ka[4], va[4];
    #pragma unroll
    for (int r = 0; r < 4; ++r) { ka[r] = make_float4(0,0,0,0); va[r] = make_float4(0,0,0,0); }

    for (int ch = 0; ch < DC/128; ++ch) {
        #pragma unroll
        for (int i = 0; i < 8; ++i) {
            const int id = t + i*256;
            const int r  = id >> 5;
            const int c  = id & 31;
            st4(&xt[r*LDSTRIDE + c*4], ld4(ctx + (row0 + r)*DC + ch*128 + c*4));
        }
        __syncthreads();

        #pragma unroll
        for (int kk = 0; kk < 8; ++kk) {
            const int kl = kk*16 + s*4;
            const int kg = ch*128 + kl;
            const float4 wk0 = ld4(Wk + (size_t)(kg+0)*DH + q*4);
            const float4 wk1 = ld4(Wk + (size_t)(kg+1)*DH + q*4);
            const float4 wk2 = ld4(Wk + (size_t)(kg+2)*DH + q*4);
            const float4 wk3 = ld4(Wk + (size_t)(kg+3)*DH + q*4);
            const float4 wv0 = ld4(Wv + (size_t)(kg+0)*DH + q*4);
            const float4 wv1 = ld4(Wv + (size_t)(kg+1)*DH + q*4);
            const float4 wv2 = ld4(Wv + (size_t)(kg+2)*DH + q*4);
            const float4 wv3 = ld4(Wv + (size_t)(kg+3)*DH + q*4);
            #pragma unroll
            for (int r = 0; r < 4; ++r) {
                const float4 xv = ld4(&xt[(g*4 + r)*LDSTRIDE + kl]);
                fma4(ka[r], xv.x, wk0); fma4(ka[r], xv.y, wk1);
                fma4(ka[r], xv.z, wk2); fma4(ka[r], xv.w, wk3);
                fma4(va[r], xv.x, wv0); fma4(va[r], xv.y, wv1);
                fma4(va[r], xv.z, wv2); fma4(va[r], xv.w, wv3);
            }
        }
        __syncthreads();
    }

    #pragma unroll
    for (int r = 0; r < 4; ++r) {
        ka[r] = add4(ka[r], sx4(ka[r], 4)); ka[r] = add4(ka[r], sx4(ka[r], 8));
        va[r] = add4(va[r], sx4(va[r], 4)); va[r] = add4(va[r], sx4(va[r], 8));
    }

    if (s == 0) {
        const float4 b4 = ld4(bk + q*4);
        #pragma unroll
        for (int r = 0; r < 4; ++r) {
            float4 o;
            o.x = elu1(ka[r].x + b4.x); o.y = elu1(ka[r].y + b4.y);
            o.z = elu1(ka[r].z + b4.z); o.w = elu1(ka[r].w + b4.w);
            st4(&sk[g*4 + r][q*4], o);
        }
    } else if (s == 1) {
        const float4 b4 = ld4(bv + q*4);
        #pragma unroll
        for (int r = 0; r < 4; ++r) {
            float4 o;
            o.x = va[r].x + b4.x; o.y = va[r].y + b4.y;
            o.z = va[r].z + b4.z; o.w = va[r].w + b4.w;
            st4(&sv[g*4 + r][q*4], o);
        }
    }
    __syncthreads();

    const int d = t >> 4, e = t & 15;
    float acc = 0.f;
    #pragma unroll 16
    for (int n = 0; n < 64; ++n) acc += sk[n][d] * sv[n][e];
    float* p = part + (size_t)blockIdx.x * 272;
    p[t] = acc;
    if (t < DH) {
        float ss = 0.f;
        #pragma unroll 16
        for (int n = 0; n < 64; ++n) ss += sk[n][t];
        p[256 + t] = ss;
    }
}

// ---------------------------------------------------------------------------
// reduce2: combine partials -> comb[b][272]
// ---------------------------------------------------------------------------
__global__ __launch_bounds__(320) void reduce2(
    const float* __restrict__ part, float* __restrict__ comb)
{
    const int b = blockIdx.x;
    const int t = threadIdx.x;
    if (t < 272) {
        float s = 0.f;
        #pragma unroll
        for (int ch = 0; ch < CHUNKS; ++ch)
            s += part[((size_t)b*CHUNKS + ch) * 272 + t];
        comb[(size_t)b*272 + t] = s;
    }
}

// ---------------------------------------------------------------------------
// q_kernel v5: exact kvr structure (256 thr, 64 rows, 4 rows/thread,
// 128-col chunks) — proven ~5 TB/s staging. Epilogue computes
// o = (Q@KtV)/(Q.Ksum+1e-6) -> o_ws. grid = B*M/64 = 512.
// ---------------------------------------------------------------------------
__global__ __launch_bounds__(256, 2) void q_kernel(
    const float* __restrict__ x,
    const float* __restrict__ Wq, const float* __restrict__ bq,
    const float* __restrict__ comb,
    float* __restrict__ o_ws)
{
    __shared__ float xt[64 * LDSTRIDE];
    __shared__ float qt[64 * DH];
    __shared__ float kts[272];

    const int t = threadIdx.x;
    const int q = t & 3;
    const int s = (t >> 2) & 3;
    const int g = t >> 4;                    // 0..15, rows g*4..g*4+3
    const size_t row0 = (size_t)blockIdx.x * 64;
    const int b = blockIdx.x >> 6;           // 64 blocks per batch

    float4 a4[4];
    #pragma unroll
    for (int r = 0; r < 4; ++r) a4[r] = make_float4(0,0,0,0);

    for (int ch = 0; ch < DM/128; ++ch) {
        #pragma unroll
        for (int i = 0; i < 8; ++i) {
            const int id = t + i*256;
            const int r  = id >> 5;
            const int c  = id & 31;
            st4(&xt[r*LDSTRIDE + c*4], ld4(x + (row0 + r)*DM + ch*128 + c*4));
        }
        __syncthreads();

        #pragma unroll
        for (int kk = 0; kk < 8; ++kk) {
            const int kl = kk*16 + s*4;
            const int kg = ch*128 + kl;
            const float4 w0 = ld4(Wq + (size_t)(kg+0)*DH + q*4);
            const float4 w1 = ld4(Wq + (size_t)(kg+1)*DH + q*4);
            const float4 w2 = ld4(Wq + (size_t)(kg+2)*DH + q*4);
            const float4 w3 = ld4(Wq + (size_t)(kg+3)*DH + q*4);
            #pragma unroll
            for (int r = 0; r < 4; ++r) {
                const float4 xv = ld4(&xt[(g*4 + r)*LDSTRIDE + kl]);
                fma4(a4[r], xv.x, w0); fma4(a4[r], xv.y, w1);
                fma4(a4[r], xv.z, w2); fma4(a4[r], xv.w, w3);
            }
        }
        __syncthreads();
    }

    #pragma unroll
    for (int r = 0; r < 4; ++r) {
        a4[r] = add4(a4[r], sx4(a4[r], 4));
        a4[r] = add4(a4[r], sx4(a4[r], 8));
    }

    if (s == 0) {
        const float4 b4 = ld4(bq + q*4);
        #pragma unroll
        for (int r = 0; r < 4; ++r) {
            float4 o;
            o.x = elu1(a4[r].x + b4.x); o.y = elu1(a4[r].y + b4.y);
            o.z = elu1(a4[r].z + b4.z); o.w = elu1(a4[r].w + b4.w);
            st4(&qt[(g*4 + r)*DH + q*4], o);
        }
    }
    if (t < 68) st4(&kts[t*4], ld4(comb + (size_t)b*272 + t*4));
    __syncthreads();

    // o per row: thread -> row t>>2, out-dims (t&3)*4..+4 (proven in round 3)
    {
        const float* qrow = &qt[(t >> 2) * DH];
        const int jj = (t & 3) * 4;
        float den = 1e-6f;
        float4 num = make_float4(0,0,0,0);
        #pragma unroll
        for (int d4 = 0; d4 < 4; ++d4) {
            const float4 q4  = ld4(&qrow[d4*4]);
            const float4 ks4 = ld4(&kts[256 + d4*4]);
            den += q4.x*ks4.x + q4.y*ks4.y + q4.z*ks4.z + q4.w*ks4.w;
            fma4(num, q4.x, ld4(&kts[(d4*4+0)*DH + jj]));
            fma4(num, q4.y, ld4(&kts[(d4*4+1)*DH + jj]));
            fma4(num, q4.z, ld4(&kts[(d4*4+2)*DH + jj]));
            fma4(num, q4.w, ld4(&kts[(d4*4+3)*DH + jj]));
        }
        const float inv = 1.0f / den;
        float4 o4; o4.x = num.x*inv; o4.y = num.y*inv; o4.z = num.z*inv; o4.w = num.w*inv;
        st4(o_ws + (row0 + (t >> 2))*DH + jj, o4);
    }
}

// ---------------------------------------------------------------------------
// proj_kernel v2: out = o @ Wo + bo. 32 rows/block, grid = B*M/32 = 1024
// (4 blocks/CU, 16 waves/CU). Wo in regs, nontemporal coalesced stores.
// ---------------------------------------------------------------------------
__global__ __launch_bounds__(256) void proj_kernel(
    const float* __restrict__ o_ws,
    const float* __restrict__ Wo, const float* __restrict__ bo,
    float* __restrict__ out)
{
    __shared__ float ol[32 * DH];
    const int t = threadIdx.x;
    const size_t row0 = (size_t)blockIdx.x * 32;

    if (t < 128) st4(&ol[t*4], ld4(o_ws + row0*DH + t*4));  // 512 floats
    float4 wreg[16];
    #pragma unroll
    for (int e = 0; e < 16; ++e) wreg[e] = ld4(Wo + (size_t)e*DM + t*4);
    const float4 bov = ld4(bo + t*4);
    __syncthreads();

    #pragma unroll 4
    for (int r = 0; r < 32; ++r) {
        float4 a = bov;
        #pragma unroll
        for (int eo = 0; eo < 4; ++eo) {
            const float4 o4 = ld4(&ol[r*DH + eo*4]);
            fma4(a, o4.x, wreg[eo*4+0]); fma4(a, o4.y, wreg[eo*4+1]);
            fma4(a, o4.z, wreg[eo*4+2]); fma4(a, o4.w, wreg[eo*4+3]);
        }
        st4nt(out + (row0 + r)*DM + t*4, a);
    }
}

// ---------------------------------------------------------------------------
extern "C" void kernel_launch(void* const* d_in, const int* in_sizes, int n_in,
                              void* d_out, int out_size, void* d_ws, size_t ws_size,
                              hipStream_t stream) {
    const float* x    = (const float*)d_in[0];
    const float* ctx  = (const float*)d_in[1];
    const float* Wq   = (const float*)d_in[2];
    const float* bq   = (const float*)d_in[3];
    const float* Wk   = (const float*)d_in[4];
    const float* bk   = (const float*)d_in[5];
    const float* Wv   = (const float*)d_in[6];
    const float* bv   = (const float*)d_in[7];
    const float* Wo   = (const float*)d_in[8];
    const float* bo   = (const float*)d_in[9];
    float* out = (float*)d_out;

    float* ws = (float*)d_ws;
    float* part = ws;                               // 512*272
    float* comb = part + (size_t)512*272;           // 8*272
    float* o_ws = comb + (size_t)B_*272;            // 32768*16

    kvr_kernel<<<dim3(B_*N_/64), dim3(256), 0, stream>>>(ctx, Wk, bk, Wv, bv, part);
    reduce2<<<dim3(B_), dim3(320), 0, stream>>>(part, comb);
    q_kernel<<<dim3(B_*M_/64), dim3(256), 0, stream>>>(x, Wq, bq, comb, o_ws);
    proj_kernel<<<dim3(B_*M_/32), dim3(256), 0, stream>>>(o_ws, Wo, bo, out);
}

// Round 8
// 117.211 us; speedup vs baseline: 1.5810x; 1.0111x over previous
//
#include <hip/hip_runtime.h>
#include <math.h>

#define B_   8
#define M_   4096
#define N_   4096
#define DM   1024
#define DC   768
#define DH   16
#define CHUNKS 64
#define LDSTRIDE 132      // 128 + 4 pad

typedef float v4f __attribute__((ext_vector_type(4)));

__device__ __forceinline__ float elu1(float t) {
    return t > 0.0f ? t + 1.0f : expf(t);
}
__device__ __forceinline__ float4 ld4(const float* p) { return *reinterpret_cast<const float4*>(p); }
__device__ __forceinline__ void  st4(float* p, float4 v) { *reinterpret_cast<float4*>(p) = v; }
__device__ __forceinline__ void  st4nt(float* p, float4 v) {
    v4f w; w.x = v.x; w.y = v.y; w.z = v.z; w.w = v.w;
    __builtin_nontemporal_store(w, reinterpret_cast<v4f*>(p));
}
__device__ __forceinline__ float4 sx4(float4 v, int m) {
    float4 r;
    r.x = __shfl_xor(v.x, m); r.y = __shfl_xor(v.y, m);
    r.z = __shfl_xor(v.z, m); r.w = __shfl_xor(v.w, m);
    return r;
}
__device__ __forceinline__ float4 add4(float4 a, float4 b) {
    float4 r; r.x=a.x+b.x; r.y=a.y+b.y; r.z=a.z+b.z; r.w=a.w+b.w; return r;
}
__device__ __forceinline__ void fma4(float4& a, float s, float4 w) {
    a.x = fmaf(s, w.x, a.x); a.y = fmaf(s, w.y, a.y);
    a.z = fmaf(s, w.z, a.z); a.w = fmaf(s, w.w, a.w);
}

// ---------------------------------------------------------------------------
// kvr_kernel: K = elu1(ctx@Wk+bk), V = ctx@Wv+bv (LDS only), fused partial
// KtV (16x16) + Ksum per 64-row block. grid = B*N/64 = 512.
// v2: next-chunk register prefetch issued before COMPUTE (hides HBM latency).
// ---------------------------------------------------------------------------
__global__ __launch_bounds__(256) void kvr_kernel(
    const float* __restrict__ ctx,
    const float* __restrict__ Wk, const float* __restrict__ bk,
    const float* __restrict__ Wv, const float* __restrict__ bv,
    float* __restrict__ part)
{
    __shared__ float xt[64 * LDSTRIDE];
    __shared__ float sk[64][DH];
    __shared__ float sv[64][DH];
    const int t = threadIdx.x;
    const int q = t & 3;
    const int s = (t >> 2) & 3;
    const int g = t >> 4;
    const size_t row0 = (size_t)blockIdx.x * 64;

    const int rs = t >> 5;           // staging row base: rows rs + i*8
    const int cs = (t & 31) * 4;     // staging col

    float4 ka[4], va[4];
    #pragma unroll
    for (int r = 0; r < 4; ++r) { ka[r] = make_float4(0,0,0,0); va[r] = make_float4(0,0,0,0); }
    float4 A[8];

#define SLOAD(ch) { \
    _Pragma("unroll") for (int i = 0; i < 8; ++i) \
        A[i] = ld4(ctx + (row0 + rs + i*8)*DC + (ch)*128 + cs); }
#define SWRITE() { \
    _Pragma("unroll") for (int i = 0; i < 8; ++i) \
        st4(&xt[(rs + i*8)*LDSTRIDE + cs], A[i]); }

    SLOAD(0);
    for (int ch = 0; ch < DC/128; ++ch) {
        SWRITE();
        __syncthreads();
        if (ch + 1 < DC/128) SLOAD(ch + 1);   // in flight during compute

        #pragma unroll
        for (int kk = 0; kk < 8; ++kk) {
            const int kl = kk*16 + s*4;
            const int kg = ch*128 + kl;
            const float4 wk0 = ld4(Wk + (size_t)(kg+0)*DH + q*4);
            const float4 wk1 = ld4(Wk + (size_t)(kg+1)*DH + q*4);
            const float4 wk2 = ld4(Wk + (size_t)(kg+2)*DH + q*4);
            const float4 wk3 = ld4(Wk + (size_t)(kg+3)*DH + q*4);
            const float4 wv0 = ld4(Wv + (size_t)(kg+0)*DH + q*4);
            const float4 wv1 = ld4(Wv + (size_t)(kg+1)*DH + q*4);
            const float4 wv2 = ld4(Wv + (size_t)(kg+2)*DH + q*4);
            const float4 wv3 = ld4(Wv + (size_t)(kg+3)*DH + q*4);
            #pragma unroll
            for (int r = 0; r < 4; ++r) {
                const float4 xv = ld4(&xt[(g*4 + r)*LDSTRIDE + kl]);
                fma4(ka[r], xv.x, wk0); fma4(ka[r], xv.y, wk1);
                fma4(ka[r], xv.z, wk2); fma4(ka[r], xv.w, wk3);
                fma4(va[r], xv.x, wv0); fma4(va[r], xv.y, wv1);
                fma4(va[r], xv.z, wv2); fma4(va[r], xv.w, wv3);
            }
        }
        __syncthreads();
    }
#undef SLOAD
#undef SWRITE

    #pragma unroll
    for (int r = 0; r < 4; ++r) {
        ka[r] = add4(ka[r], sx4(ka[r], 4)); ka[r] = add4(ka[r], sx4(ka[r], 8));
        va[r] = add4(va[r], sx4(va[r], 4)); va[r] = add4(va[r], sx4(va[r], 8));
    }

    if (s == 0) {
        const float4 b4 = ld4(bk + q*4);
        #pragma unroll
        for (int r = 0; r < 4; ++r) {
            float4 o;
            o.x = elu1(ka[r].x + b4.x); o.y = elu1(ka[r].y + b4.y);
            o.z = elu1(ka[r].z + b4.z); o.w = elu1(ka[r].w + b4.w);
            st4(&sk[g*4 + r][q*4], o);
        }
    } else if (s == 1) {
        const float4 b4 = ld4(bv + q*4);
        #pragma unroll
        for (int r = 0; r < 4; ++r) {
            float4 o;
            o.x = va[r].x + b4.x; o.y = va[r].y + b4.y;
            o.z = va[r].z + b4.z; o.w = va[r].w + b4.w;
            st4(&sv[g*4 + r][q*4], o);
        }
    }
    __syncthreads();

    const int d = t >> 4, e = t & 15;
    float acc = 0.f;
    #pragma unroll 16
    for (int n = 0; n < 64; ++n) acc += sk[n][d] * sv[n][e];
    float* p = part + (size_t)blockIdx.x * 272;
    p[t] = acc;
    if (t < DH) {
        float ss = 0.f;
        #pragma unroll 16
        for (int n = 0; n < 64; ++n) ss += sk[n][t];
        p[256 + t] = ss;
    }
}

// ---------------------------------------------------------------------------
// reduce2: combine partials -> comb[b][272]
// ---------------------------------------------------------------------------
__global__ __launch_bounds__(320) void reduce2(
    const float* __restrict__ part, float* __restrict__ comb)
{
    const int b = blockIdx.x;
    const int t = threadIdx.x;
    if (t < 272) {
        float s = 0.f;
        #pragma unroll
        for (int ch = 0; ch < CHUNKS; ++ch)
            s += part[((size_t)b*CHUNKS + ch) * 272 + t];
        comb[(size_t)b*272 + t] = s;
    }
}

// ---------------------------------------------------------------------------
// q_kernel v6: kvr structure + register prefetch. Epilogue computes
// o = (Q@KtV)/(Q.Ksum+1e-6) -> o_ws. grid = B*M/64 = 512.
// ---------------------------------------------------------------------------
__global__ __launch_bounds__(256) void q_kernel(
    const float* __restrict__ x,
    const float* __restrict__ Wq, const float* __restrict__ bq,
    const float* __restrict__ comb,
    float* __restrict__ o_ws)
{
    __shared__ float xt[64 * LDSTRIDE];
    __shared__ float qt[64 * DH];
    __shared__ float kts[272];

    const int t = threadIdx.x;
    const int q = t & 3;
    const int s = (t >> 2) & 3;
    const int g = t >> 4;
    const size_t row0 = (size_t)blockIdx.x * 64;
    const int b = blockIdx.x >> 6;

    const int rs = t >> 5;
    const int cs = (t & 31) * 4;

    float4 a4[4];
    #pragma unroll
    for (int r = 0; r < 4; ++r) a4[r] = make_float4(0,0,0,0);
    float4 A[8];

#define SLOAD(ch) { \
    _Pragma("unroll") for (int i = 0; i < 8; ++i) \
        A[i] = ld4(x + (row0 + rs + i*8)*DM + (ch)*128 + cs); }
#define SWRITE() { \
    _Pragma("unroll") for (int i = 0; i < 8; ++i) \
        st4(&xt[(rs + i*8)*LDSTRIDE + cs], A[i]); }

    SLOAD(0);
    for (int ch = 0; ch < DM/128; ++ch) {
        SWRITE();
        __syncthreads();
        if (ch + 1 < DM/128) SLOAD(ch + 1);

        #pragma unroll
        for (int kk = 0; kk < 8; ++kk) {
            const int kl = kk*16 + s*4;
            const int kg = ch*128 + kl;
            const float4 w0 = ld4(Wq + (size_t)(kg+0)*DH + q*4);
            const float4 w1 = ld4(Wq + (size_t)(kg+1)*DH + q*4);
            const float4 w2 = ld4(Wq + (size_t)(kg+2)*DH + q*4);
            const float4 w3 = ld4(Wq + (size_t)(kg+3)*DH + q*4);
            #pragma unroll
            for (int r = 0; r < 4; ++r) {
                const float4 xv = ld4(&xt[(g*4 + r)*LDSTRIDE + kl]);
                fma4(a4[r], xv.x, w0); fma4(a4[r], xv.y, w1);
                fma4(a4[r], xv.z, w2); fma4(a4[r], xv.w, w3);
            }
        }
        __syncthreads();
    }
#undef SLOAD
#undef SWRITE

    #pragma unroll
    for (int r = 0; r < 4; ++r) {
        a4[r] = add4(a4[r], sx4(a4[r], 4));
        a4[r] = add4(a4[r], sx4(a4[r], 8));
    }

    if (s == 0) {
        const float4 b4 = ld4(bq + q*4);
        #pragma unroll
        for (int r = 0; r < 4; ++r) {
            float4 o;
            o.x = elu1(a4[r].x + b4.x); o.y = elu1(a4[r].y + b4.y);
            o.z = elu1(a4[r].z + b4.z); o.w = elu1(a4[r].w + b4.w);
            st4(&qt[(g*4 + r)*DH + q*4], o);
        }
    }
    if (t < 68) st4(&kts[t*4], ld4(comb + (size_t)b*272 + t*4));
    __syncthreads();

    {
        const float* qrow = &qt[(t >> 2) * DH];
        const int jj = (t & 3) * 4;
        float den = 1e-6f;
        float4 num = make_float4(0,0,0,0);
        #pragma unroll
        for (int d4 = 0; d4 < 4; ++d4) {
            const float4 q4  = ld4(&qrow[d4*4]);
            const float4 ks4 = ld4(&kts[256 + d4*4]);
            den += q4.x*ks4.x + q4.y*ks4.y + q4.z*ks4.z + q4.w*ks4.w;
            fma4(num, q4.x, ld4(&kts[(d4*4+0)*DH + jj]));
            fma4(num, q4.y, ld4(&kts[(d4*4+1)*DH + jj]));
            fma4(num, q4.z, ld4(&kts[(d4*4+2)*DH + jj]));
            fma4(num, q4.w, ld4(&kts[(d4*4+3)*DH + jj]));
        }
        const float inv = 1.0f / den;
        float4 o4; o4.x = num.x*inv; o4.y = num.y*inv; o4.z = num.z*inv; o4.w = num.w*inv;
        st4(o_ws + (row0 + (t >> 2))*DH + jj, o4);
    }
}

// ---------------------------------------------------------------------------
// proj_kernel v3: out = o @ Wo + bo. 16 rows/block, grid = B*M/16 = 2048
// (8 blocks/CU). Wo in regs, o in 1KB LDS, nontemporal coalesced stores.
// ---------------------------------------------------------------------------
__global__ __launch_bounds__(256) void proj_kernel(
    const float* __restrict__ o_ws,
    const float* __restrict__ Wo, const float* __restrict__ bo,
    float* __restrict__ out)
{
    __shared__ float ol[16 * DH];
    const int t = threadIdx.x;
    const size_t row0 = (size_t)blockIdx.x * 16;

    if (t < 64) st4(&ol[t*4], ld4(o_ws + row0*DH + t*4));   // 256 floats
    float4 wreg[16];
    #pragma unroll
    for (int e = 0; e < 16; ++e) wreg[e] = ld4(Wo + (size_t)e*DM + t*4);
    const float4 bov = ld4(bo + t*4);
    __syncthreads();

    #pragma unroll
    for (int r = 0; r < 16; ++r) {
        float4 a = bov;
        #pragma unroll
        for (int eo = 0; eo < 4; ++eo) {
            const float4 o4 = ld4(&ol[r*DH + eo*4]);
            fma4(a, o4.x, wreg[eo*4+0]); fma4(a, o4.y, wreg[eo*4+1]);
            fma4(a, o4.z, wreg[eo*4+2]); fma4(a, o4.w, wreg[eo*4+3]);
        }
        st4nt(out + (row0 + r)*DM + t*4, a);
    }
}

// ---------------------------------------------------------------------------
extern "C" void kernel_launch(void* const* d_in, const int* in_sizes, int n_in,
                              void* d_out, int out_size, void* d_ws, size_t ws_size,
                              hipStream_t stream) {
    const float* x    = (const float*)d_in[0];
    const float* ctx  = (const float*)d_in[1];
    const float* Wq   = (const float*)d_in[2];
    const float* bq   = (const float*)d_in[3];
    const float* Wk   = (const float*)d_in[4];
    const float* bk   = (const float*)d_in[5];
    const float* Wv   = (const float*)d_in[6];
    const float* bv   = (const float*)d_in[7];
    const float* Wo   = (const float*)d_in[8];
    const float* bo   = (const float*)d_in[9];
    float* out = (float*)d_out;

    float* ws = (float*)d_ws;
    float* part = ws;                               // 512*272
    float* comb = part + (size_t)512*272;           // 8*272
    float* o_ws = comb + (size_t)B_*272;            // 32768*16

    kvr_kernel<<<dim3(B_*N_/64), dim3(256), 0, stream>>>(ctx, Wk, bk, Wv, bv, part);
    reduce2<<<dim3(B_), dim3(320), 0, stream>>>(part, comb);
    q_kernel<<<dim3(B_*M_/64), dim3(256), 0, stream>>>(x, Wq, bq, comb, o_ws);
    proj_kernel<<<dim3(B_*M_/16), dim3(256), 0, stream>>>(o_ws, Wo, bo, out);
}

// Round 9
// 112.450 us; speedup vs baseline: 1.6479x; 1.0423x over previous
//
#include <hip/hip_runtime.h>
#include <math.h>

#define B_   8
#define M_   4096
#define N_   4096
#define DM   1024
#define DC   768
#define DH   16
#define CHUNKS 64
#define LDSTRIDE 132      // 128 + 4 pad

typedef float v4f __attribute__((ext_vector_type(4)));

__device__ __forceinline__ float elu1(float t) {
    return t > 0.0f ? t + 1.0f : expf(t);
}
__device__ __forceinline__ float4 ld4(const float* p) { return *reinterpret_cast<const float4*>(p); }
__device__ __forceinline__ void  st4(float* p, float4 v) { *reinterpret_cast<float4*>(p) = v; }
__device__ __forceinline__ void  st4nt(float* p, float4 v) {
    v4f w; w.x = v.x; w.y = v.y; w.z = v.z; w.w = v.w;
    __builtin_nontemporal_store(w, reinterpret_cast<v4f*>(p));
}
__device__ __forceinline__ float4 sx4(float4 v, int m) {
    float4 r;
    r.x = __shfl_xor(v.x, m); r.y = __shfl_xor(v.y, m);
    r.z = __shfl_xor(v.z, m); r.w = __shfl_xor(v.w, m);
    return r;
}
__device__ __forceinline__ float4 add4(float4 a, float4 b) {
    float4 r; r.x=a.x+b.x; r.y=a.y+b.y; r.z=a.z+b.z; r.w=a.w+b.w; return r;
}
__device__ __forceinline__ void fma4(float4& a, float s, float4 w) {
    a.x = fmaf(s, w.x, a.x); a.y = fmaf(s, w.y, a.y);
    a.z = fmaf(s, w.z, a.z); a.w = fmaf(s, w.w, a.w);
}

// ---------------------------------------------------------------------------
// fused1: blocks [0,512): kvr — K=elu1(ctx@Wk+bk), V=ctx@Wv+bv (LDS only),
//                         fused partial KtV(16x16)+Ksum -> part.
//         blocks [512,1024): Q = elu1(x@Wq+bq) -> q_ws (2 MB).
// Both read streams run concurrently; grid = 1024, block = 256.
// ---------------------------------------------------------------------------
__global__ __launch_bounds__(256) void fused1(
    const float* __restrict__ ctx,
    const float* __restrict__ Wk, const float* __restrict__ bk,
    const float* __restrict__ Wv, const float* __restrict__ bv,
    const float* __restrict__ x,
    const float* __restrict__ Wq, const float* __restrict__ bq,
    float* __restrict__ part, float* __restrict__ q_ws)
{
    __shared__ float xt[64 * LDSTRIDE];
    __shared__ float sk[64][DH];
    __shared__ float sv[64][DH];

    const int t = threadIdx.x;
    const int q = t & 3;
    const int s = (t >> 2) & 3;
    const int g = t >> 4;
    const int rs = t >> 5;           // staging row base: rows rs + i*8
    const int cs = (t & 31) * 4;     // staging col

    if (blockIdx.x < B_*N_/64) {
        // ---------------- kvr path ----------------
        const size_t row0 = (size_t)blockIdx.x * 64;
        float4 ka[4], va[4];
        #pragma unroll
        for (int r = 0; r < 4; ++r) { ka[r] = make_float4(0,0,0,0); va[r] = make_float4(0,0,0,0); }
        float4 A[8];

#define SLOAD(ch) { \
        _Pragma("unroll") for (int i = 0; i < 8; ++i) \
            A[i] = ld4(ctx + (row0 + rs + i*8)*DC + (ch)*128 + cs); }
#define SWRITE() { \
        _Pragma("unroll") for (int i = 0; i < 8; ++i) \
            st4(&xt[(rs + i*8)*LDSTRIDE + cs], A[i]); }

        SLOAD(0);
        for (int ch = 0; ch < DC/128; ++ch) {
            SWRITE();
            __syncthreads();
            if (ch + 1 < DC/128) SLOAD(ch + 1);

            #pragma unroll
            for (int kk = 0; kk < 8; ++kk) {
                const int kl = kk*16 + s*4;
                const int kg = ch*128 + kl;
                const float4 wk0 = ld4(Wk + (size_t)(kg+0)*DH + q*4);
                const float4 wk1 = ld4(Wk + (size_t)(kg+1)*DH + q*4);
                const float4 wk2 = ld4(Wk + (size_t)(kg+2)*DH + q*4);
                const float4 wk3 = ld4(Wk + (size_t)(kg+3)*DH + q*4);
                const float4 wv0 = ld4(Wv + (size_t)(kg+0)*DH + q*4);
                const float4 wv1 = ld4(Wv + (size_t)(kg+1)*DH + q*4);
                const float4 wv2 = ld4(Wv + (size_t)(kg+2)*DH + q*4);
                const float4 wv3 = ld4(Wv + (size_t)(kg+3)*DH + q*4);
                #pragma unroll
                for (int r = 0; r < 4; ++r) {
                    const float4 xv = ld4(&xt[(g*4 + r)*LDSTRIDE + kl]);
                    fma4(ka[r], xv.x, wk0); fma4(ka[r], xv.y, wk1);
                    fma4(ka[r], xv.z, wk2); fma4(ka[r], xv.w, wk3);
                    fma4(va[r], xv.x, wv0); fma4(va[r], xv.y, wv1);
                    fma4(va[r], xv.z, wv2); fma4(va[r], xv.w, wv3);
                }
            }
            __syncthreads();
        }
#undef SLOAD
#undef SWRITE

        #pragma unroll
        for (int r = 0; r < 4; ++r) {
            ka[r] = add4(ka[r], sx4(ka[r], 4)); ka[r] = add4(ka[r], sx4(ka[r], 8));
            va[r] = add4(va[r], sx4(va[r], 4)); va[r] = add4(va[r], sx4(va[r], 8));
        }

        if (s == 0) {
            const float4 b4 = ld4(bk + q*4);
            #pragma unroll
            for (int r = 0; r < 4; ++r) {
                float4 o;
                o.x = elu1(ka[r].x + b4.x); o.y = elu1(ka[r].y + b4.y);
                o.z = elu1(ka[r].z + b4.z); o.w = elu1(ka[r].w + b4.w);
                st4(&sk[g*4 + r][q*4], o);
            }
        } else if (s == 1) {
            const float4 b4 = ld4(bv + q*4);
            #pragma unroll
            for (int r = 0; r < 4; ++r) {
                float4 o;
                o.x = va[r].x + b4.x; o.y = va[r].y + b4.y;
                o.z = va[r].z + b4.z; o.w = va[r].w + b4.w;
                st4(&sv[g*4 + r][q*4], o);
            }
        }
        __syncthreads();

        const int d = t >> 4, e = t & 15;
        float acc = 0.f;
        #pragma unroll 16
        for (int n = 0; n < 64; ++n) acc += sk[n][d] * sv[n][e];
        float* p = part + (size_t)blockIdx.x * 272;
        p[t] = acc;
        if (t < DH) {
            float ss = 0.f;
            #pragma unroll 16
            for (int n = 0; n < 64; ++n) ss += sk[n][t];
            p[256 + t] = ss;
        }
    } else {
        // ---------------- Q path ----------------
        const size_t row0 = (size_t)(blockIdx.x - B_*N_/64) * 64;
        float4 a4[4];
        #pragma unroll
        for (int r = 0; r < 4; ++r) a4[r] = make_float4(0,0,0,0);
        float4 A[8];

#define SLOAD(ch) { \
        _Pragma("unroll") for (int i = 0; i < 8; ++i) \
            A[i] = ld4(x + (row0 + rs + i*8)*DM + (ch)*128 + cs); }
#define SWRITE() { \
        _Pragma("unroll") for (int i = 0; i < 8; ++i) \
            st4(&xt[(rs + i*8)*LDSTRIDE + cs], A[i]); }

        SLOAD(0);
        for (int ch = 0; ch < DM/128; ++ch) {
            SWRITE();
            __syncthreads();
            if (ch + 1 < DM/128) SLOAD(ch + 1);

            #pragma unroll
            for (int kk = 0; kk < 8; ++kk) {
                const int kl = kk*16 + s*4;
                const int kg = ch*128 + kl;
                const float4 w0 = ld4(Wq + (size_t)(kg+0)*DH + q*4);
                const float4 w1 = ld4(Wq + (size_t)(kg+1)*DH + q*4);
                const float4 w2 = ld4(Wq + (size_t)(kg+2)*DH + q*4);
                const float4 w3 = ld4(Wq + (size_t)(kg+3)*DH + q*4);
                #pragma unroll
                for (int r = 0; r < 4; ++r) {
                    const float4 xv = ld4(&xt[(g*4 + r)*LDSTRIDE + kl]);
                    fma4(a4[r], xv.x, w0); fma4(a4[r], xv.y, w1);
                    fma4(a4[r], xv.z, w2); fma4(a4[r], xv.w, w3);
                }
            }
            __syncthreads();
        }
#undef SLOAD
#undef SWRITE

        #pragma unroll
        for (int r = 0; r < 4; ++r) {
            a4[r] = add4(a4[r], sx4(a4[r], 4));
            a4[r] = add4(a4[r], sx4(a4[r], 8));
        }

        if (s == 0) {
            const float4 b4 = ld4(bq + q*4);
            #pragma unroll
            for (int r = 0; r < 4; ++r) {
                float4 o;
                o.x = elu1(a4[r].x + b4.x); o.y = elu1(a4[r].y + b4.y);
                o.z = elu1(a4[r].z + b4.z); o.w = elu1(a4[r].w + b4.w);
                st4(q_ws + (row0 + g*4 + r)*DH + q*4, o);
            }
        }
    }
}

// ---------------------------------------------------------------------------
// reduce2: combine partials -> comb[b][272] (256 KtV d-major + 16 Ksum)
// ---------------------------------------------------------------------------
__global__ __launch_bounds__(320) void reduce2(
    const float* __restrict__ part, float* __restrict__ comb)
{
    const int b = blockIdx.x;
    const int t = threadIdx.x;
    if (t < 272) {
        float s = 0.f;
        #pragma unroll
        for (int ch = 0; ch < CHUNKS; ++ch)
            s += part[((size_t)b*CHUNKS + ch) * 272 + t];
        comb[(size_t)b*272 + t] = s;
    }
}

// ---------------------------------------------------------------------------
// oproj: o = (Q@KtV)/(Q.Ksum+1e-6); out = o@Wo + bo.
// Q is 2 MB (L2/L3-hot). 16 rows/block, grid = B*M/16 = 2048.
// Wo in regs, nontemporal coalesced 1KB/wave stores — near-pure write stream.
// ---------------------------------------------------------------------------
__global__ __launch_bounds__(256) void oproj(
    const float* __restrict__ q_ws, const float* __restrict__ comb,
    const float* __restrict__ Wo, const float* __restrict__ bo,
    float* __restrict__ out)
{
    __shared__ float ql[16 * DH];
    __shared__ float ol[16 * DH];
    __shared__ float kts[272];

    const int t = threadIdx.x;
    const size_t row0 = (size_t)blockIdx.x * 16;
    const int b = blockIdx.x >> 8;          // 256 blocks per batch

    // issue Wo register loads early (independent of syncs)
    float4 wreg[16];
    #pragma unroll
    for (int e = 0; e < 16; ++e) wreg[e] = ld4(Wo + (size_t)e*DM + t*4);
    const float4 bov = ld4(bo + t*4);

    if (t < 64) st4(&ql[t*4], ld4(q_ws + row0*DH + t*4));            // 16 rows of Q
    else if (t < 132) st4(&kts[(t-64)*4], ld4(comb + (size_t)b*272 + (t-64)*4));
    __syncthreads();

    // o: threads 0..63 -> row t>>2, out-dims (t&3)*4..+4
    if (t < 64) {
        const float* qrow = &ql[(t >> 2) * DH];
        const int jj = (t & 3) * 4;
        float den = 1e-6f;
        float4 num = make_float4(0,0,0,0);
        #pragma unroll
        for (int d4 = 0; d4 < 4; ++d4) {
            const float4 q4  = ld4(&qrow[d4*4]);
            const float4 ks4 = ld4(&kts[256 + d4*4]);
            den += q4.x*ks4.x + q4.y*ks4.y + q4.z*ks4.z + q4.w*ks4.w;
            fma4(num, q4.x, ld4(&kts[(d4*4+0)*DH + jj]));
            fma4(num, q4.y, ld4(&kts[(d4*4+1)*DH + jj]));
            fma4(num, q4.z, ld4(&kts[(d4*4+2)*DH + jj]));
            fma4(num, q4.w, ld4(&kts[(d4*4+3)*DH + jj]));
        }
        const float inv = 1.0f / den;
        float4 o4; o4.x = num.x*inv; o4.y = num.y*inv; o4.z = num.z*inv; o4.w = num.w*inv;
        st4(&ol[(t >> 2)*DH + jj], o4);
    }
    __syncthreads();

    // projection: thread owns cols 4t..4t+3 for 16 rows
    #pragma unroll
    for (int r = 0; r < 16; ++r) {
        float4 a = bov;
        #pragma unroll
        for (int eo = 0; eo < 4; ++eo) {
            const float4 o4 = ld4(&ol[r*DH + eo*4]);
            fma4(a, o4.x, wreg[eo*4+0]); fma4(a, o4.y, wreg[eo*4+1]);
            fma4(a, o4.z, wreg[eo*4+2]); fma4(a, o4.w, wreg[eo*4+3]);
        }
        st4nt(out + (row0 + r)*DM + t*4, a);
    }
}

// ---------------------------------------------------------------------------
extern "C" void kernel_launch(void* const* d_in, const int* in_sizes, int n_in,
                              void* d_out, int out_size, void* d_ws, size_t ws_size,
                              hipStream_t stream) {
    const float* x    = (const float*)d_in[0];
    const float* ctx  = (const float*)d_in[1];
    const float* Wq   = (const float*)d_in[2];
    const float* bq   = (const float*)d_in[3];
    const float* Wk   = (const float*)d_in[4];
    const float* bk   = (const float*)d_in[5];
    const float* Wv   = (const float*)d_in[6];
    const float* bv   = (const float*)d_in[7];
    const float* Wo   = (const float*)d_in[8];
    const float* bo   = (const float*)d_in[9];
    float* out = (float*)d_out;

    float* ws = (float*)d_ws;
    float* part = ws;                               // 512*272
    float* comb = part + (size_t)512*272;           // 8*272
    float* q_ws = comb + (size_t)B_*272;            // 32768*16 = 2 MB

    fused1<<<dim3(B_*N_/64 + B_*M_/64), dim3(256), 0, stream>>>(
        ctx, Wk, bk, Wv, bv, x, Wq, bq, part, q_ws);
    reduce2<<<dim3(B_), dim3(320), 0, stream>>>(part, comb);
    oproj<<<dim3(B_*M_/16), dim3(256), 0, stream>>>(q_ws, comb, Wo, bo, out);
}